// Round 16
// baseline (146.667 us; speedup 1.0000x reference)
//
#include <hip/hip_runtime.h>
#include <hip/hip_bf16.h>
#include <math.h>

#define B_  8
#define N_  128
#define T_  1024
#define D_  512

typedef __hip_bfloat16 bf16;
typedef __attribute__((ext_vector_type(8))) short short8v;
typedef __attribute__((ext_vector_type(4))) float f32x4;
typedef __attribute__((ext_vector_type(4))) float float4v;
typedef __attribute__((ext_vector_type(4))) unsigned int uint4v;

__device__ __forceinline__ void gload16(const void* g, void* l) {
  __builtin_amdgcn_global_load_lds(
      (const __attribute__((address_space(1))) void*)g,
      (__attribute__((address_space(3))) void*)l, 16, 0, 0);
}

__device__ __forceinline__ void f2b4s(const float* in, bf16* out) {
  float4v v = *(const float4v*)in;
  bf16 o[4] = {bf16(v.x), bf16(v.y), bf16(v.z), bf16(v.w)};
  *(ulong1*)out = *(ulong1*)o;
}

// XCD-chunked bijective swizzle (n % 8 == 0)
__device__ __forceinline__ int xswz(int p, int n) {
  return (p & 7) * (n >> 3) + (p >> 3);
}

// wave-level: idx(b,t) = one-hot column of alignments row
__device__ __forceinline__ int eval_idx(const float* __restrict__ algn,
                                        int b, int t, int lane) {
  const float* r = algn + ((size_t)b * T_ + t) * N_;
  unsigned long long m0 = __ballot(r[lane] > 0.5f);
  unsigned long long m1 = __ballot(r[lane + 64] > 0.5f);
  return m0 ? (__ffsll(m0) - 1) : (m1 ? (__ffsll(m1) - 1 + 64) : 0);
}
// first t with idx(b,t) >= n (1024 if none)
__device__ __forceinline__ int lower_bound_t(const float* __restrict__ algn,
                                             int b, int n, int lane) {
  int lo = 0, hi = 1024;
  while (lo < hi) {
    int mid = (lo + hi) >> 1;
    if (eval_idx(algn, b, mid, lane) >= n) hi = mid; else lo = mid + 1;
  }
  return lo;
}

// ---------------------------------------------------------------------------
// mega-prep. Block ranges:
//  [0, 10241)       flat elementwise, g = bid*256+tid:
//    [0,1048576) x->xb | ->1245184 inw | ->1310720 outw | ->1572864 botw
//    | ->1703936 w1 repack | ->2490368 w2 repack | ->2621440 emb->embB
//    | ->2621442 lacc zero
//  [10241, 12289)   idx ballot, 4 rows/block
//  [12289, 12545)   dur/segst via wave binary search, 4 (b,n)/block
//  [12545, 12929)   lqQ = lq @ wq^T + bq (3x512), wave-per-output
//  [12929, 13953)   pool per (b,n) block (self-computed segment)
// ---------------------------------------------------------------------------
__global__ __launch_bounds__(256) void k_prep(
    const float* __restrict__ x, const float* __restrict__ inw,
    const float* __restrict__ outw, const float* __restrict__ botw,
    const float* __restrict__ c1w, const float* __restrict__ c2w,
    const float* __restrict__ emb, const float* __restrict__ lq,
    const float* __restrict__ algn, const float* __restrict__ inb,
    bf16* __restrict__ xb, bf16* __restrict__ inwb, bf16* __restrict__ outwb,
    bf16* __restrict__ botwb, bf16* __restrict__ w1tb, bf16* __restrict__ w2tb,
    bf16* __restrict__ embB, bf16* __restrict__ lqQb, int* __restrict__ idx,
    int* __restrict__ dur, int* __restrict__ segst,
    float* __restrict__ lacc, float* __restrict__ pooled)
{
  const int bid = blockIdx.x;
  const int tid = threadIdx.x;
  const int lane = tid & 63;
  const int w = tid >> 6;
  if (bid < 10241) {
    int g = bid * 256 + tid;
    if (g < 1048576) {
      f2b4s(x + (size_t)g * 4, xb + (size_t)g * 4);
    } else if (g < 1245184) {
      int i = g - 1048576;
      f2b4s(inw + (size_t)i * 4, inwb + (size_t)i * 4);
    } else if (g < 1310720) {
      int i = g - 1245184;
      f2b4s(outw + (size_t)i * 4, outwb + (size_t)i * 4);
    } else if (g < 1572864) {
      int i = g - 1310720;
      f2b4s(botw + (size_t)i * 4, botwb + (size_t)i * 4);
    } else if (g < 1703936) {
      int i = g - 1572864;              // 512*256
      int kk = i & 255, c = i >> 8;
      float v = 0.f;
      if (kk < 195) { int tap = kk / 65, ii = kk - tap * 65; v = c1w[c * 195 + ii * 3 + tap]; }
      w1tb[i] = bf16(v);
    } else if (g < 2490368) {
      int i = g - 1703936;              // 512*1536
      int kk = i % 1536, co = i / 1536;
      int tap = kk >> 9, ci = kk & 511;
      w2tb[i] = bf16(c2w[co * 1536 + ci * 3 + tap]);
    } else if (g < 2621440) {
      int i = g - 2490368;              // 131072 items (1024*512/4)
      f2b4s(emb + (size_t)i * 4, embB + (size_t)i * 4);
    } else if (g < 2621442) {
      lacc[g - 2621440] = 0.f;
    }
  } else if (bid < 12289) {
    int row = (bid - 10241) * 4 + w;
    int b = row >> 10, t = row & 1023;
    int n = eval_idx(algn, b, t, lane);
    if (lane == 0) idx[row] = n;
  } else if (bid < 12545) {
    int wid = (bid - 12289) * 4 + w;
    int b = wid >> 7, n = wid & 127;
    int l1 = lower_bound_t(algn, b, n, lane);
    int l2 = lower_bound_t(algn, b, n + 1, lane);
    if (lane == 0) { segst[wid] = l1; dur[wid] = l2 - l1; }
  } else if (bid < 12929) {
    int wid = (bid - 12545) * 4 + w;    // [0, 1536)
    int r = wid >> 9, d = wid & 511;
    float acc = 0.f;
    for (int k = lane; k < 512; k += 64)
      acc = fmaf(lq[r * 512 + k], inw[(size_t)d * 512 + k], acc);
#pragma unroll
    for (int off = 32; off; off >>= 1) acc += __shfl_xor(acc, off);
    if (lane == 0) lqQb[r * 512 + d] = bf16(acc + inb[d]);
  } else {
    __shared__ int sseg[2];
    int bn = bid - 12929;
    int b = bn >> 7, n = bn & 127;
    if (w == 0) {
      int l1 = lower_bound_t(algn, b, n, lane);
      int l2 = lower_bound_t(algn, b, n + 1, lane);
      if (lane == 0) { sseg[0] = l1; sseg[1] = l2 - l1; }
    }
    __syncthreads();
    int s0 = sseg[0], cnt = sseg[1];
    int d0 = tid;
    float a0 = 0.f, a1 = 0.f;
    for (int i = 0; i < cnt; ++i) {
      const float* xr = x + (size_t)(b * T_ + s0 + i) * D_;
      a0 += xr[d0];
      a1 += xr[d0 + 256];
    }
    float inv = 1.f / ((float)cnt + 1e-8f);
    pooled[(size_t)bn * D_ + d0] = a0 * inv;
    pooled[(size_t)bn * D_ + d0 + 256] = a1 * inv;
  }
}

// ---------------------------------------------------------------------------
// bf16 MFMA GEMM body: 128x128 tile, BK=64, 8 waves (2x4, 64x32 each),
// depth-4 ring + prefetch-2 + SINGLE barrier per K-step. Counted vmcnt 8/4/0.
//   EPI: 0 none, 1 silu, 3 raw partial (split-K), 4 none + fused L1/L2 loss
//   APAD: A physical row = m + 2*(m>>10); CMODE: C row = m + 2*(m>>10) + 1
// ---------------------------------------------------------------------------
template<int EPI, int APAD, int CMODE, typename CT>
__device__ __forceinline__ void mgemm_body(
    const bf16* __restrict__ A, int lda,
    const bf16* __restrict__ W, int ldw,
    const float* __restrict__ bias,
    CT* __restrict__ C, int ldc,
    int M, int Nc, int K, int bx, int by, int bz,
    const float* __restrict__ xref, float* __restrict__ lacc)
{
  __shared__ __align__(16) short As[4][8192];   // 128 rows x 64 k
  __shared__ __align__(16) short Bs[4][8192];   // 128 rows x 64 k
  const int tid = threadIdx.x;
  const int m0 = by * 128;
  const int n0 = bx * 128;
  const int kbase = bz * K;
  const int w = tid >> 6, lane = tid & 63;
  const int wm = (w >> 2) * 64, wn = (w & 3) * 32;
  const int lr = lane & 15;
  const int cg = lane >> 4;                      // k-chunk group 0..3

  const int rg = tid >> 3;                       // 0..63
  const int soff = (((tid & 7) ^ (rg & 7)) << 3);
  int gA0 = m0 + rg, gA1 = m0 + rg + 64;
  int ar0 = APAD ? gA0 + ((gA0 >> 10) << 1) : gA0;
  int ar1 = APAD ? gA1 + ((gA1 >> 10) << 1) : gA1;
  const size_t aOff0 = (size_t)ar0 * lda + kbase + soff;
  const size_t aOff1 = (size_t)ar1 * lda + kbase + soff;
  const size_t wOff0 = (size_t)(n0 + rg) * ldw + kbase + soff;
  const size_t wOff1 = (size_t)(n0 + rg + 64) * ldw + kbase + soff;

  const int nt = K >> 6;

#define STAGE_(tt, buf) do { \
    size_t kk_ = (size_t)(tt) * 64; \
    gload16(A + aOff0 + kk_, &As[buf][tid * 8]); \
    gload16(A + aOff1 + kk_, &As[buf][4096 + tid * 8]); \
    gload16(W + wOff0 + kk_, &Bs[buf][tid * 8]); \
    gload16(W + wOff1 + kk_, &Bs[buf][4096 + tid * 8]); \
  } while (0)

  STAGE_(0, 0);
  if (nt > 1) STAGE_(1, 1);

  f32x4 acc[4][2] = {};
  int cur = 0;
  for (int t = 0; t < nt; ++t) {
    if (t + 2 < nt) {
      STAGE_(t + 2, (cur + 2) & 3);
      asm volatile("s_waitcnt vmcnt(8)" ::: "memory");
    } else if (t + 1 < nt) {
      asm volatile("s_waitcnt vmcnt(4)" ::: "memory");
    } else {
      asm volatile("s_waitcnt vmcnt(0)" ::: "memory");
    }
    __builtin_amdgcn_sched_barrier(0);
    __builtin_amdgcn_s_barrier();            // the ONLY barrier per K-step
    __builtin_amdgcn_sched_barrier(0);
#pragma unroll
    for (int h = 0; h < 2; ++h) {
      short8v af[4], bfv[2];
#pragma unroll
      for (int i = 0; i < 4; ++i) {
        int rr = wm + i * 16 + lr;
        af[i] = *(const short8v*)&As[cur][rr * 64 + (((h * 4 + cg) ^ (rr & 7)) << 3)];
      }
#pragma unroll
      for (int j = 0; j < 2; ++j) {
        int rr = wn + j * 16 + lr;
        bfv[j] = *(const short8v*)&Bs[cur][rr * 64 + (((h * 4 + cg) ^ (rr & 7)) << 3)];
      }
      __builtin_amdgcn_s_setprio(1);
#pragma unroll
      for (int i = 0; i < 4; ++i)
#pragma unroll
        for (int j = 0; j < 2; ++j)
          acc[i][j] = __builtin_amdgcn_mfma_f32_16x16x32_bf16(af[i], bfv[j], acc[i][j], 0, 0, 0);
      __builtin_amdgcn_s_setprio(0);
    }
    cur = (cur + 1) & 3;
  }
#undef STAGE_

  if (EPI == 3) C += (size_t)bz * M * ldc;
  const int orow = (lane >> 4) * 4;
  const int ocol = lane & 15;
  float la = 0.f, lb = 0.f;
#pragma unroll
  for (int i = 0; i < 4; ++i) {
#pragma unroll
    for (int q = 0; q < 4; ++q) {
      int gm = m0 + wm + i * 16 + orow + q;
      int cr = CMODE ? gm + ((gm >> 10) << 1) + 1 : gm;
#pragma unroll
      for (int j = 0; j < 2; ++j) {
        int gn = n0 + wn + j * 16 + ocol;
        float v = acc[i][j][q];
        if (EPI != 3) v += bias[gn];
        if (EPI == 1) v = v / (1.f + __expf(-v));
        if (EPI == 4) {
          float diff = xref[(size_t)gm * Nc + gn] - v;
          la += fabsf(diff);
          lb += diff * diff;
        }
        C[(size_t)cr * ldc + gn] = (CT)v;
      }
    }
  }
  if (EPI == 4) {
    __shared__ float sh1[8], sh2[8];
#pragma unroll
    for (int off = 32; off; off >>= 1) { la += __shfl_xor(la, off); lb += __shfl_xor(lb, off); }
    if (lane == 0) { sh1[w] = la; sh2[w] = lb; }
    __syncthreads();
    if (tid == 0) {
      float s1 = 0.f, s2 = 0.f;
#pragma unroll
      for (int i = 0; i < 8; ++i) { s1 += sh1[i]; s2 += sh2[i]; }
      atomicAdd(&lacc[0], s1);
      atomicAdd(&lacc[1], s2);
    }
  }
}

// merged kv + embQ projections: logical [0,512) kv, [512,544) embQ
__global__ __launch_bounds__(512, 2) void k_kvq(
    const bf16* __restrict__ xb, const bf16* __restrict__ embB,
    const bf16* __restrict__ inwb, const float* __restrict__ inb,
    bf16* __restrict__ kvB, bf16* __restrict__ qbufB)
{
  int bid = xswz(blockIdx.x, 544);
  if (bid < 512) {
    mgemm_body<0, 0, 0, bf16>(xb, 512, inwb + 512 * 512, 512, inb + 512,
                              kvB, 1024, 8192, 1024, 512,
                              bid & 7, bid >> 3, 0, nullptr, nullptr);
  } else {
    int i = bid - 512;                  // [0, 32): embQ 1024x512
    mgemm_body<0, 0, 0, bf16>(embB, 512, inwb, 512, inb,
                              qbufB, 512, 1024, 512, 512,
                              i & 3, i >> 2, 0, nullptr, nullptr);
  }
}

// out projection -> bf16 (grid 128 = 4 x 32, XCD-swizzled)
__global__ __launch_bounds__(512, 2) void k_outp(
    const bf16* __restrict__ ctxB, const bf16* __restrict__ outwb,
    const float* __restrict__ outb, bf16* __restrict__ attnB)
{
  int l = xswz(blockIdx.x, 128);
  mgemm_body<0, 0, 0, bf16>(ctxB, 512, outwb, 512, outb, attnB, 512,
                            4096, 512, 512, l & 3, l >> 2, 0,
                            nullptr, nullptr);
}

// bottleneck split-K partials -> bf16 (grid 32 x 4(kz), XCD-swizzled on xy)
__global__ __launch_bounds__(512, 2) void k_bot(
    const bf16* __restrict__ qnB, const bf16* __restrict__ botwb,
    bf16* __restrict__ botPB)
{
  int l = xswz(blockIdx.x, 32);
  mgemm_body<3, 0, 0, bf16>(qnB, 2048, botwb, 2048, nullptr, botPB, 512,
                            1024, 512, 512, l & 3, l >> 2, blockIdx.y,
                            nullptr, nullptr);
}

// conv1: silu -> bf16 y1p (padded rows) (grid 256 = 4 x 64)
__global__ __launch_bounds__(512, 2) void k_conv1(
    const bf16* __restrict__ azc, const bf16* __restrict__ w1tb,
    const float* __restrict__ c1b, bf16* __restrict__ y1p)
{
  int l = xswz(blockIdx.x, 256);
  mgemm_body<1, 0, 1, bf16>(azc, 256, w1tb, 256, c1b, y1p, 512,
                            8192, 512, 256, l & 3, l >> 2, 0,
                            nullptr, nullptr);
}

// conv2 + fused loss (grid 256 = 4 x 64)
__global__ __launch_bounds__(512, 2) void k_conv2(
    const bf16* __restrict__ y1p, const bf16* __restrict__ w2tb,
    const float* __restrict__ c2b, float* __restrict__ out,
    const float* __restrict__ x, float* __restrict__ lacc)
{
  int l = xswz(blockIdx.x, 256);
  mgemm_body<4, 1, 0, float>(y1p, 512, w2tb, 1536, c2b, out, 512,
                             8192, 512, 1536, l & 3, l >> 2, 0,
                             x, lacc);
}

// ---------------------------------------------------------------------------
// segment attention, one pass, all 8 heads at once, 8-frame chunks (ILP).
// wave w = query j: j==0 -> embQ row bn; j>0 -> lqQ row j-1 (shared).
// ---------------------------------------------------------------------------
__global__ __launch_bounds__(256) void k_attn(
    const bf16* __restrict__ embQ, const bf16* __restrict__ lqQ,
    const bf16* __restrict__ kv,
    const int* __restrict__ segst, const int* __restrict__ dur,
    bf16* __restrict__ ctx)
{
  int bn = blockIdx.x;
  int b = bn >> 7;
  int w = threadIdx.x >> 6;
  int lane = threadIdx.x & 63;
  int s0 = segst[bn], cnt = dur[bn];
  if (cnt == 0) { s0 = 0; cnt = T_; }
  size_t qrow = (size_t)bn * 4 + w;
  const bf16* kvb = kv + ((size_t)b * T_ + s0) * 1024;

  const bf16* qptr = (w == 0) ? embQ + (size_t)bn * 512
                              : lqQ + (size_t)(w - 1) * 512;
  float qf[8];
  {
    uint4v qv = *(const uint4v*)(qptr + lane * 8);
#pragma unroll
    for (int i = 0; i < 4; ++i) {
      unsigned u = qv[i];
      qf[2 * i]     = __uint_as_float(u << 16);
      qf[2 * i + 1] = __uint_as_float(u & 0xffff0000u);
    }
  }

  float m = -1e30f, l = 0.f;
  float o[8] = {};
  for (int s = 0; s < cnt; s += 8) {
    float sc8[8];
#pragma unroll
    for (int u = 0; u < 8; ++u) {
      int ss = s + u;
      int sscl = (ss < cnt) ? ss : (cnt - 1);
      uint4v kr = *(const uint4v*)(kvb + (size_t)sscl * 1024 + lane * 8);
      float d0 = 0.f;
#pragma unroll
      for (int i = 0; i < 4; ++i) {
        unsigned uu = kr[i];
        d0 = fmaf(qf[2 * i],     __uint_as_float(uu << 16),         d0);
        d0 = fmaf(qf[2 * i + 1], __uint_as_float(uu & 0xffff0000u), d0);
      }
      d0 += __shfl_xor(d0, 1);
      d0 += __shfl_xor(d0, 2);
      d0 += __shfl_xor(d0, 4);
      sc8[u] = (ss < cnt) ? d0 * 0.125f : -1e30f;
    }
    float cmax = fmaxf(
        fmaxf(fmaxf(sc8[0], sc8[1]), fmaxf(sc8[2], sc8[3])),
        fmaxf(fmaxf(sc8[4], sc8[5]), fmaxf(sc8[6], sc8[7])));
    float mn = fmaxf(m, cmax);
    float c = __expf(m - mn);
    float p[8];
    float psum = 0.f;
#pragma unroll
    for (int u = 0; u < 8; ++u) { p[u] = __expf(sc8[u] - mn); psum += p[u]; }
    l = l * c + psum;
#pragma unroll
    for (int k = 0; k < 8; ++k) o[k] *= c;
#pragma unroll
    for (int u = 0; u < 8; ++u) {
      int ss = s + u;
      int sscl = (ss < cnt) ? ss : (cnt - 1);
      uint4v vr = *(const uint4v*)(kvb + (size_t)sscl * 1024 + 512 + lane * 8);
      float pu = p[u];
#pragma unroll
      for (int i = 0; i < 4; ++i) {
        unsigned uu = vr[i];
        o[2 * i]     = fmaf(pu, __uint_as_float(uu << 16),         o[2 * i]);
        o[2 * i + 1] = fmaf(pu, __uint_as_float(uu & 0xffff0000u), o[2 * i + 1]);
      }
    }
    m = mn;
  }
  float invl = 1.f / l;
  bf16 ob[8];
#pragma unroll
  for (int k = 0; k < 8; ++k) ob[k] = bf16(o[k] * invl);
  *(uint4v*)(ctx + qrow * 512 + lane * 8) = *(uint4v*)ob;
}

// ---------------------------------------------------------------------------
// layernorm of (queries + attn_out[bf16]) -> bf16 qn
// ---------------------------------------------------------------------------
__global__ __launch_bounds__(256) void k_ln(
    const float* __restrict__ emb, const float* __restrict__ lq,
    const bf16* __restrict__ attn,
    const float* __restrict__ g, const float* __restrict__ bb,
    bf16* __restrict__ qn)
{
  int r = blockIdx.x * 4 + (threadIdx.x >> 6);
  int lane = threadIdx.x & 63;
  int bn = r >> 2, j = r & 3;
  const float* src = (j == 0) ? emb + (size_t)bn * D_ : lq + (size_t)(j - 1) * D_;
  float h[8];
  float s = 0.f, s2 = 0.f;
#pragma unroll
  for (int i = 0; i < 8; ++i) {
    int d = i * 64 + lane;
    float v = src[d] + __bfloat162float(attn[(size_t)r * D_ + d]);
    h[i] = v; s += v; s2 += v * v;
  }
#pragma unroll
  for (int off = 32; off; off >>= 1) { s += __shfl_xor(s, off); s2 += __shfl_xor(s2, off); }
  float mean = s * (1.f / 512.f);
  float var = s2 * (1.f / 512.f) - mean * mean;
  float inv = rsqrtf(var + 1e-5f);
#pragma unroll
  for (int i = 0; i < 8; ++i) {
    int d = i * 64 + lane;
    qn[(size_t)r * D_ + d] = bf16((h[i] - mean) * inv * g[d] + bb[d]);
  }
}

// ---------------------------------------------------------------------------
// fused bottleneck epilogue (bf16 partials) + mu/logvar/z + KL partial
// ---------------------------------------------------------------------------
__global__ __launch_bounds__(128) void k_muz(
    const bf16* __restrict__ part, const float* __restrict__ bbias,
    const float* __restrict__ pooled,
    const float* __restrict__ mu_w, const float* __restrict__ mu_b,
    const float* __restrict__ lv_w, const float* __restrict__ lv_b,
    const float* __restrict__ eps, float* __restrict__ z, float* __restrict__ klpart)
{
  __shared__ float hs[512];
  __shared__ float ms[64], ls[64];
  int bn = blockIdx.x;
  int tid = threadIdx.x;
  const size_t S = 1024ull * 512;
  for (int i = tid; i < 512; i += 128) {
    size_t off = (size_t)bn * 512 + i;
    float v = __bfloat162float(part[off]) + __bfloat162float(part[off + S]) +
              __bfloat162float(part[off + 2 * S]) + __bfloat162float(part[off + 3 * S]) +
              bbias[i];
    v = v / (1.f + __expf(-v));
    hs[i] = v + pooled[off];
  }
  __syncthreads();
  int ld = tid & 63;
  const float* wrow = (tid < 64) ? (mu_w + (size_t)ld * 512) : (lv_w + (size_t)ld * 512);
  float acc = 0.f;
  for (int k = 0; k < 512; ++k) acc = fmaf(hs[k], wrow[k], acc);
  acc += (tid < 64) ? mu_b[ld] : lv_b[ld];
  if (tid < 64) ms[ld] = acc; else ls[ld] = acc;
  __syncthreads();
  if (tid < 64) {
    float mu = ms[ld], lv = ls[ld];
    z[(size_t)bn * 64 + ld] = mu + eps[(size_t)bn * 64 + ld] * expf(0.5f * lv);
    float klt = 1.f + lv - mu * mu - expf(lv);
#pragma unroll
    for (int off = 32; off; off >>= 1) klt += __shfl_xor(klt, off);
    if (ld == 0) klpart[bn] = klt;
  }
}

// ---------------------------------------------------------------------------
// im2col A for conv1 (azc bf16 [8192][256]), 8 k-elems/thread, 16B stores,
// + y1p pad-row zeroing fused. grid = 1024 blocks.
// ---------------------------------------------------------------------------
__global__ __launch_bounds__(256) void k_azc(
    const float* __restrict__ z, const int* __restrict__ idx,
    const int* __restrict__ segst, const int* __restrict__ dur,
    bf16* __restrict__ azc, bf16* __restrict__ y1p)
{
  int gid = blockIdx.x * 256 + threadIdx.x;     // [0, 262144)
  if (blockIdx.x < 32) {
    int d = gid & 511;
    int rest = gid >> 9;
    int which = rest & 1;
    int b = rest >> 1;
    int rr = which ? (T_ + 1) : 0;
    y1p[(size_t)(b * (T_ + 2) + rr) * 512 + d] = bf16(0.f);
  }
  int m = gid >> 5;                             // [0, 8192)
  int k0 = (gid & 31) * 8;
  int b = m >> 10, t = m & 1023;
  bf16 tmp[8];
#pragma unroll
  for (int e = 0; e < 8; ++e) {
    int k = k0 + e;
    float v = 0.f;
    if (k < 195) {
      int tap = k / 65, c = k - tap * 65;
      int tt = t + tap - 1;
      if (tt >= 0 && tt < T_) {
        int iv = idx[b * T_ + tt];
        if (c < 64) v = z[(size_t)(b * N_ + iv) * 64 + c];
        else {
          int s0 = segst[b * N_ + iv];
          float d2 = (float)dur[b * N_ + iv];
          v = ((float)(tt - s0) + 0.5f) / d2;
        }
      }
    }
    tmp[e] = bf16(v);
  }
  *(uint4v*)(azc + (size_t)m * 256 + k0) = *(uint4v*)tmp;
}

// ---------------------------------------------------------------------------
// final scalar outputs
// ---------------------------------------------------------------------------
__global__ __launch_bounds__(256) void k_final(
    const float* __restrict__ klpart, const float* __restrict__ lacc,
    const float* __restrict__ klw, float* __restrict__ out)
{
  __shared__ float sa[4];
  float a = 0.f;
  for (int i = threadIdx.x; i < 1024; i += 256) a += klpart[i];
#pragma unroll
  for (int off = 32; off; off >>= 1) a += __shfl_xor(a, off);
  int w = threadIdx.x >> 6, lane = threadIdx.x & 63;
  if (lane == 0) sa[w] = a;
  __syncthreads();
  if (threadIdx.x == 0) {
    float kl = sa[0] + sa[1] + sa[2] + sa[3];
    out[(size_t)B_ * T_ * D_]     = -0.5f * kl * klw[0];
    out[(size_t)B_ * T_ * D_ + 1] = (lacc[0] + lacc[1]) / (float)(B_ * T_ * D_);
  }
}

// ---------------------------------------------------------------------------
extern "C" void kernel_launch(void* const* d_in, const int* in_sizes, int n_in,
                              void* d_out, int out_size, void* d_ws, size_t ws_size,
                              hipStream_t stream)
{
  const float* emb  = (const float*)d_in[0];
  const float* algn = (const float*)d_in[1];
  const float* x    = (const float*)d_in[2];
  const float* klw  = (const float*)d_in[5];
  const float* eps  = (const float*)d_in[6];
  const float* lq   = (const float*)d_in[7];
  const float* inw  = (const float*)d_in[8];
  const float* inb  = (const float*)d_in[9];
  const float* outw = (const float*)d_in[10];
  const float* outb = (const float*)d_in[11];
  const float* lng  = (const float*)d_in[12];
  const float* lnb  = (const float*)d_in[13];
  const float* botw = (const float*)d_in[14];
  const float* botb = (const float*)d_in[15];
  const float* muw  = (const float*)d_in[16];
  const float* mub  = (const float*)d_in[17];
  const float* lvw  = (const float*)d_in[18];
  const float* lvb  = (const float*)d_in[19];
  const float* c1w  = (const float*)d_in[20];
  const float* c1b  = (const float*)d_in[21];
  const float* c2w  = (const float*)d_in[22];
  const float* c2b  = (const float*)d_in[23];
  float* out = (float*)d_out;

  float* ws = (float*)d_ws;
  size_t o = 0;
  auto allocF = [&](size_t n) { float* p = ws + o; o += n; return p; };
  auto allocB = [&](size_t n) { bf16* p = (bf16*)(ws + o); o += (n + 1) / 2; return p; };

  bf16* kvB    = allocB(8192ull * 1024);
  bf16* xb     = allocB(8192ull * 512);     // dead after kv GEMM; azc aliases it
  bf16* qryB   = allocB(4096ull * 512);     // embB + lqQb live here
  bf16* qbufB  = allocB(4096ull * 512);     // embQ (1024x512 used)
  bf16* ctxB   = allocB(4096ull * 512);
  bf16* qnB    = allocB(4096ull * 512);
  bf16* inwb   = allocB(1536ull * 512);
  bf16* outwb  = allocB(512ull * 512);
  bf16* botwb  = allocB(512ull * 2048);
  bf16* w1tb   = allocB(512ull * 256);
  bf16* w2tb   = allocB(512ull * 1536);
  bf16* y1p    = allocB(8ull * (T_ + 2) * 512);
  float* attnF  = allocF(4096ull * 512);    // attnB(bf16) then botPB(bf16)
  float* pooled = allocF(1024ull * 512);
  float* zbuf   = allocF(1024ull * 64);
  float* klpart = allocF(1024);
  float* lacc   = allocF(2);
  int* idx   = (int*)(ws + o); o += 8192;
  int* segst = (int*)(ws + o); o += 1024;
  int* durI  = (int*)(ws + o); o += 1024;
  bf16* azc  = xb;
  bf16* embB = qryB;
  bf16* lqQb = qryB + 1024ull * 512;
  bf16* attnB = (bf16*)attnF;               // dead after k_ln
  bf16* botPB = (bf16*)attnF;               // 4 planes x 1024x512 bf16 = 4MB

  // 1. mega-prep
  k_prep<<<dim3(13953), 256, 0, stream>>>(
      x, inw, outw, botw, c1w, c2w, emb, lq, algn, inb,
      xb, inwb, outwb, botwb, w1tb, w2tb, embB, lqQb, idx, durI, segst,
      lacc, pooled);

  // 2. kv + embQ projections (merged, XCD-swizzled, 512 thr)
  k_kvq<<<dim3(544), 512, 0, stream>>>(xb, embB, inwb, inb, kvB, qbufB);

  // 3. attention (8-frame chunks)
  k_attn<<<dim3(B_ * N_), 256, 0, stream>>>(qbufB, lqQb, kvB, segst, durI, ctxB);

  // 4. out projection -> bf16 attnB
  k_outp<<<dim3(128), 512, 0, stream>>>(ctxB, outwb, outb, attnB);

  // 5. layernorm
  k_ln<<<dim3(1024), 256, 0, stream>>>(emb, lq, attnB, lng, lnb, qnB);

  // 6. bottleneck split-K=4 partials (bf16)
  k_bot<<<dim3(32, 4), 512, 0, stream>>>(qnB, botwb, botPB);

  // 7. fused bot-epilogue + VAE + KL
  k_muz<<<dim3(B_ * N_), 128, 0, stream>>>(
      botPB, botb, pooled, muw, mub, lvw, lvb, eps, zbuf, klpart);

  // 8. conv1 im2col (vectorized) + y1p pad zeroing
  k_azc<<<dim3(1024), 256, 0, stream>>>(zbuf, idx, segst, durI, azc, y1p);

  // 9. conv1
  k_conv1<<<dim3(256), 512, 0, stream>>>(azc, w1tb, c1b, y1p);

  // 10. conv2 + fused loss
  k_conv2<<<dim3(256), 512, 0, stream>>>(y1p, w2tb, c2b, out, x, lacc);

  // 11. final scalars
  k_final<<<dim3(1), 256, 0, stream>>>(klpart, lacc, klw, out);
}

// Round 17
// 143.393 us; speedup vs baseline: 1.0228x; 1.0228x over previous
//
#include <hip/hip_runtime.h>
#include <hip/hip_bf16.h>
#include <math.h>

#define B_  8
#define N_  128
#define T_  1024
#define D_  512

typedef __hip_bfloat16 bf16;
typedef __attribute__((ext_vector_type(8))) short short8v;
typedef __attribute__((ext_vector_type(4))) float f32x4;
typedef __attribute__((ext_vector_type(4))) float float4v;
typedef __attribute__((ext_vector_type(4))) unsigned int uint4v;

__device__ __forceinline__ void gload16(const void* g, void* l) {
  __builtin_amdgcn_global_load_lds(
      (const __attribute__((address_space(1))) void*)g,
      (__attribute__((address_space(3))) void*)l, 16, 0, 0);
}

__device__ __forceinline__ void f2b4s(const float* in, bf16* out) {
  float4v v = *(const float4v*)in;
  bf16 o[4] = {bf16(v.x), bf16(v.y), bf16(v.z), bf16(v.w)};
  *(ulong1*)out = *(ulong1*)o;
}

// XCD-chunked bijective swizzle (n % 8 == 0)
__device__ __forceinline__ int xswz(int p, int n) {
  return (p & 7) * (n >> 3) + (p >> 3);
}

// wave-level: idx(b,t) = one-hot column of alignments row
__device__ __forceinline__ int eval_idx(const float* __restrict__ algn,
                                        int b, int t, int lane) {
  const float* r = algn + ((size_t)b * T_ + t) * N_;
  unsigned long long m0 = __ballot(r[lane] > 0.5f);
  unsigned long long m1 = __ballot(r[lane + 64] > 0.5f);
  return m0 ? (__ffsll(m0) - 1) : (m1 ? (__ffsll(m1) - 1 + 64) : 0);
}
// first t with idx(b,t) >= n (1024 if none)
__device__ __forceinline__ int lower_bound_t(const float* __restrict__ algn,
                                             int b, int n, int lane) {
  int lo = 0, hi = 1024;
  while (lo < hi) {
    int mid = (lo + hi) >> 1;
    if (eval_idx(algn, b, mid, lane) >= n) hi = mid; else lo = mid + 1;
  }
  return lo;
}

// ---------------------------------------------------------------------------
// mega-prep. Block ranges:
//  [0, 10241)       flat elementwise, g = bid*256+tid:
//    [0,1048576) x->xb | ->1245184 inw | ->1310720 outw | ->1572864 botw
//    | ->1703936 w1 repack | ->2490368 w2 repack | ->2621440 emb->embB
//    | ->2621442 lacc zero
//  [10241, 12289)   idx ballot, 4 rows/block
//  [12289, 12545)   dur/segst via wave binary search, 4 (b,n)/block
//  [12545, 12929)   lqQ = lq @ wq^T + bq (3x512), wave-per-output
//  [12929, 13953)   pool per (b,n) block (self-computed segment)
// ---------------------------------------------------------------------------
__global__ __launch_bounds__(256) void k_prep(
    const float* __restrict__ x, const float* __restrict__ inw,
    const float* __restrict__ outw, const float* __restrict__ botw,
    const float* __restrict__ c1w, const float* __restrict__ c2w,
    const float* __restrict__ emb, const float* __restrict__ lq,
    const float* __restrict__ algn, const float* __restrict__ inb,
    bf16* __restrict__ xb, bf16* __restrict__ inwb, bf16* __restrict__ outwb,
    bf16* __restrict__ botwb, bf16* __restrict__ w1tb, bf16* __restrict__ w2tb,
    bf16* __restrict__ embB, bf16* __restrict__ lqQb, int* __restrict__ idx,
    int* __restrict__ dur, int* __restrict__ segst,
    float* __restrict__ lacc, float* __restrict__ pooled)
{
  const int bid = blockIdx.x;
  const int tid = threadIdx.x;
  const int lane = tid & 63;
  const int w = tid >> 6;
  if (bid < 10241) {
    int g = bid * 256 + tid;
    if (g < 1048576) {
      f2b4s(x + (size_t)g * 4, xb + (size_t)g * 4);
    } else if (g < 1245184) {
      int i = g - 1048576;
      f2b4s(inw + (size_t)i * 4, inwb + (size_t)i * 4);
    } else if (g < 1310720) {
      int i = g - 1245184;
      f2b4s(outw + (size_t)i * 4, outwb + (size_t)i * 4);
    } else if (g < 1572864) {
      int i = g - 1310720;
      f2b4s(botw + (size_t)i * 4, botwb + (size_t)i * 4);
    } else if (g < 1703936) {
      int i = g - 1572864;              // 512*256
      int kk = i & 255, c = i >> 8;
      float v = 0.f;
      if (kk < 195) { int tap = kk / 65, ii = kk - tap * 65; v = c1w[c * 195 + ii * 3 + tap]; }
      w1tb[i] = bf16(v);
    } else if (g < 2490368) {
      int i = g - 1703936;              // 512*1536
      int kk = i % 1536, co = i / 1536;
      int tap = kk >> 9, ci = kk & 511;
      w2tb[i] = bf16(c2w[co * 1536 + ci * 3 + tap]);
    } else if (g < 2621440) {
      int i = g - 2490368;              // 131072 items (1024*512/4)
      f2b4s(emb + (size_t)i * 4, embB + (size_t)i * 4);
    } else if (g < 2621442) {
      lacc[g - 2621440] = 0.f;
    }
  } else if (bid < 12289) {
    int row = (bid - 10241) * 4 + w;
    int b = row >> 10, t = row & 1023;
    int n = eval_idx(algn, b, t, lane);
    if (lane == 0) idx[row] = n;
  } else if (bid < 12545) {
    int wid = (bid - 12289) * 4 + w;
    int b = wid >> 7, n = wid & 127;
    int l1 = lower_bound_t(algn, b, n, lane);
    int l2 = lower_bound_t(algn, b, n + 1, lane);
    if (lane == 0) { segst[wid] = l1; dur[wid] = l2 - l1; }
  } else if (bid < 12929) {
    int wid = (bid - 12545) * 4 + w;    // [0, 1536)
    int r = wid >> 9, d = wid & 511;
    float acc = 0.f;
    for (int k = lane; k < 512; k += 64)
      acc = fmaf(lq[r * 512 + k], inw[(size_t)d * 512 + k], acc);
#pragma unroll
    for (int off = 32; off; off >>= 1) acc += __shfl_xor(acc, off);
    if (lane == 0) lqQb[r * 512 + d] = bf16(acc + inb[d]);
  } else {
    __shared__ int sseg[2];
    int bn = bid - 12929;
    int b = bn >> 7, n = bn & 127;
    if (w == 0) {
      int l1 = lower_bound_t(algn, b, n, lane);
      int l2 = lower_bound_t(algn, b, n + 1, lane);
      if (lane == 0) { sseg[0] = l1; sseg[1] = l2 - l1; }
    }
    __syncthreads();
    int s0 = sseg[0], cnt = sseg[1];
    int d0 = tid;
    float a0 = 0.f, a1 = 0.f;
    for (int i = 0; i < cnt; ++i) {
      const float* xr = x + (size_t)(b * T_ + s0 + i) * D_;
      a0 += xr[d0];
      a1 += xr[d0 + 256];
    }
    float inv = 1.f / ((float)cnt + 1e-8f);
    pooled[(size_t)bn * D_ + d0] = a0 * inv;
    pooled[(size_t)bn * D_ + d0 + 256] = a1 * inv;
  }
}

// ---------------------------------------------------------------------------
// bf16 MFMA GEMM body: 128x128 tile, BK=64, 8 waves (2x4, 64x32 each),
// depth-4 ring + prefetch-2 + SINGLE barrier per K-step. Counted vmcnt 8/4/0.
//   EPI: 0 none, 1 silu, 3 raw partial (split-K), 4 none + fused L1/L2 loss
//   APAD: A physical row = m + 2*(m>>10); CMODE: C row = m + 2*(m>>10) + 1
// ---------------------------------------------------------------------------
template<int EPI, int APAD, int CMODE, typename CT>
__device__ __forceinline__ void mgemm_body(
    const bf16* __restrict__ A, int lda,
    const bf16* __restrict__ W, int ldw,
    const float* __restrict__ bias,
    CT* __restrict__ C, int ldc,
    int M, int Nc, int K, int bx, int by, int bz,
    const float* __restrict__ xref, float* __restrict__ lacc)
{
  __shared__ __align__(16) short As[4][8192];   // 128 rows x 64 k
  __shared__ __align__(16) short Bs[4][8192];   // 128 rows x 64 k
  const int tid = threadIdx.x;
  const int m0 = by * 128;
  const int n0 = bx * 128;
  const int kbase = bz * K;
  const int w = tid >> 6, lane = tid & 63;
  const int wm = (w >> 2) * 64, wn = (w & 3) * 32;
  const int lr = lane & 15;
  const int cg = lane >> 4;                      // k-chunk group 0..3

  const int rg = tid >> 3;                       // 0..63
  const int soff = (((tid & 7) ^ (rg & 7)) << 3);
  int gA0 = m0 + rg, gA1 = m0 + rg + 64;
  int ar0 = APAD ? gA0 + ((gA0 >> 10) << 1) : gA0;
  int ar1 = APAD ? gA1 + ((gA1 >> 10) << 1) : gA1;
  const size_t aOff0 = (size_t)ar0 * lda + kbase + soff;
  const size_t aOff1 = (size_t)ar1 * lda + kbase + soff;
  const size_t wOff0 = (size_t)(n0 + rg) * ldw + kbase + soff;
  const size_t wOff1 = (size_t)(n0 + rg + 64) * ldw + kbase + soff;

  const int nt = K >> 6;

#define STAGE_(tt, buf) do { \
    size_t kk_ = (size_t)(tt) * 64; \
    gload16(A + aOff0 + kk_, &As[buf][tid * 8]); \
    gload16(A + aOff1 + kk_, &As[buf][4096 + tid * 8]); \
    gload16(W + wOff0 + kk_, &Bs[buf][tid * 8]); \
    gload16(W + wOff1 + kk_, &Bs[buf][4096 + tid * 8]); \
  } while (0)

  STAGE_(0, 0);
  if (nt > 1) STAGE_(1, 1);

  f32x4 acc[4][2] = {};
  int cur = 0;
  for (int t = 0; t < nt; ++t) {
    if (t + 2 < nt) {
      STAGE_(t + 2, (cur + 2) & 3);
      asm volatile("s_waitcnt vmcnt(8)" ::: "memory");
    } else if (t + 1 < nt) {
      asm volatile("s_waitcnt vmcnt(4)" ::: "memory");
    } else {
      asm volatile("s_waitcnt vmcnt(0)" ::: "memory");
    }
    __builtin_amdgcn_sched_barrier(0);
    __builtin_amdgcn_s_barrier();            // the ONLY barrier per K-step
    __builtin_amdgcn_sched_barrier(0);
#pragma unroll
    for (int h = 0; h < 2; ++h) {
      short8v af[4], bfv[2];
#pragma unroll
      for (int i = 0; i < 4; ++i) {
        int rr = wm + i * 16 + lr;
        af[i] = *(const short8v*)&As[cur][rr * 64 + (((h * 4 + cg) ^ (rr & 7)) << 3)];
      }
#pragma unroll
      for (int j = 0; j < 2; ++j) {
        int rr = wn + j * 16 + lr;
        bfv[j] = *(const short8v*)&Bs[cur][rr * 64 + (((h * 4 + cg) ^ (rr & 7)) << 3)];
      }
      __builtin_amdgcn_s_setprio(1);
#pragma unroll
      for (int i = 0; i < 4; ++i)
#pragma unroll
        for (int j = 0; j < 2; ++j)
          acc[i][j] = __builtin_amdgcn_mfma_f32_16x16x32_bf16(af[i], bfv[j], acc[i][j], 0, 0, 0);
      __builtin_amdgcn_s_setprio(0);
    }
    cur = (cur + 1) & 3;
  }
#undef STAGE_

  if (EPI == 3) C += (size_t)bz * M * ldc;
  const int orow = (lane >> 4) * 4;
  const int ocol = lane & 15;
  float la = 0.f, lb = 0.f;
#pragma unroll
  for (int i = 0; i < 4; ++i) {
#pragma unroll
    for (int q = 0; q < 4; ++q) {
      int gm = m0 + wm + i * 16 + orow + q;
      int cr = CMODE ? gm + ((gm >> 10) << 1) + 1 : gm;
#pragma unroll
      for (int j = 0; j < 2; ++j) {
        int gn = n0 + wn + j * 16 + ocol;
        float v = acc[i][j][q];
        if (EPI != 3) v += bias[gn];
        if (EPI == 1) v = v / (1.f + __expf(-v));
        if (EPI == 4) {
          float diff = xref[(size_t)gm * Nc + gn] - v;
          la += fabsf(diff);
          lb += diff * diff;
        }
        C[(size_t)cr * ldc + gn] = (CT)v;
      }
    }
  }
  if (EPI == 4) {
    __shared__ float sh1[8], sh2[8];
#pragma unroll
    for (int off = 32; off; off >>= 1) { la += __shfl_xor(la, off); lb += __shfl_xor(lb, off); }
    if (lane == 0) { sh1[w] = la; sh2[w] = lb; }
    __syncthreads();
    if (tid == 0) {
      float s1 = 0.f, s2 = 0.f;
#pragma unroll
      for (int i = 0; i < 8; ++i) { s1 += sh1[i]; s2 += sh2[i]; }
      atomicAdd(&lacc[0], s1);
      atomicAdd(&lacc[1], s2);
    }
  }
}

// merged kv + embQ projections: logical [0,512) kv, [512,544) embQ
__global__ __launch_bounds__(512, 2) void k_kvq(
    const bf16* __restrict__ xb, const bf16* __restrict__ embB,
    const bf16* __restrict__ inwb, const float* __restrict__ inb,
    bf16* __restrict__ kvB, bf16* __restrict__ qbufB)
{
  int bid = xswz(blockIdx.x, 544);
  if (bid < 512) {
    mgemm_body<0, 0, 0, bf16>(xb, 512, inwb + 512 * 512, 512, inb + 512,
                              kvB, 1024, 8192, 1024, 512,
                              bid & 7, bid >> 3, 0, nullptr, nullptr);
  } else {
    int i = bid - 512;                  // [0, 32): embQ 1024x512
    mgemm_body<0, 0, 0, bf16>(embB, 512, inwb, 512, inb,
                              qbufB, 512, 1024, 512, 512,
                              i & 3, i >> 2, 0, nullptr, nullptr);
  }
}

// out projection -> bf16 (grid 128 = 4 x 32, XCD-swizzled)
__global__ __launch_bounds__(512, 2) void k_outp(
    const bf16* __restrict__ ctxB, const bf16* __restrict__ outwb,
    const float* __restrict__ outb, bf16* __restrict__ attnB)
{
  int l = xswz(blockIdx.x, 128);
  mgemm_body<0, 0, 0, bf16>(ctxB, 512, outwb, 512, outb, attnB, 512,
                            4096, 512, 512, l & 3, l >> 2, 0,
                            nullptr, nullptr);
}

// bottleneck split-K partials (grid 32 x 4(kz), XCD-swizzled on xy)
__global__ __launch_bounds__(512, 2) void k_bot(
    const bf16* __restrict__ qnB, const bf16* __restrict__ botwb,
    float* __restrict__ botP)
{
  int l = xswz(blockIdx.x, 32);
  mgemm_body<3, 0, 0, float>(qnB, 2048, botwb, 2048, nullptr, botP, 512,
                             1024, 512, 512, l & 3, l >> 2, blockIdx.y,
                             nullptr, nullptr);
}

// conv1: silu -> bf16 y1p (padded rows) (grid 256 = 4 x 64)
__global__ __launch_bounds__(512, 2) void k_conv1(
    const bf16* __restrict__ azc, const bf16* __restrict__ w1tb,
    const float* __restrict__ c1b, bf16* __restrict__ y1p)
{
  int l = xswz(blockIdx.x, 256);
  mgemm_body<1, 0, 1, bf16>(azc, 256, w1tb, 256, c1b, y1p, 512,
                            8192, 512, 256, l & 3, l >> 2, 0,
                            nullptr, nullptr);
}

// conv2 + fused loss (grid 256 = 4 x 64)
__global__ __launch_bounds__(512, 2) void k_conv2(
    const bf16* __restrict__ y1p, const bf16* __restrict__ w2tb,
    const float* __restrict__ c2b, float* __restrict__ out,
    const float* __restrict__ x, float* __restrict__ lacc)
{
  int l = xswz(blockIdx.x, 256);
  mgemm_body<4, 1, 0, float>(y1p, 512, w2tb, 1536, c2b, out, 512,
                             8192, 512, 1536, l & 3, l >> 2, 0,
                             x, lacc);
}

// ---------------------------------------------------------------------------
// segment attention, one pass, all 8 heads at once, 4-frame chunks.
// wave w = query j: j==0 -> embQ row bn; j>0 -> lqQ row j-1 (shared).
// ---------------------------------------------------------------------------
__global__ __launch_bounds__(256) void k_attn(
    const bf16* __restrict__ embQ, const bf16* __restrict__ lqQ,
    const bf16* __restrict__ kv,
    const int* __restrict__ segst, const int* __restrict__ dur,
    bf16* __restrict__ ctx)
{
  int bn = blockIdx.x;
  int b = bn >> 7;
  int w = threadIdx.x >> 6;
  int lane = threadIdx.x & 63;
  int s0 = segst[bn], cnt = dur[bn];
  if (cnt == 0) { s0 = 0; cnt = T_; }
  size_t qrow = (size_t)bn * 4 + w;
  const bf16* kvb = kv + ((size_t)b * T_ + s0) * 1024;

  const bf16* qptr = (w == 0) ? embQ + (size_t)bn * 512
                              : lqQ + (size_t)(w - 1) * 512;
  float qf[8];
  {
    uint4v qv = *(const uint4v*)(qptr + lane * 8);
#pragma unroll
    for (int i = 0; i < 4; ++i) {
      unsigned u = qv[i];
      qf[2 * i]     = __uint_as_float(u << 16);
      qf[2 * i + 1] = __uint_as_float(u & 0xffff0000u);
    }
  }

  float m = -1e30f, l = 0.f;
  float o[8] = {};
  for (int s = 0; s < cnt; s += 4) {
    float sc4[4];
#pragma unroll
    for (int u = 0; u < 4; ++u) {
      int ss = s + u;
      int sscl = (ss < cnt) ? ss : (cnt - 1);
      uint4v kr = *(const uint4v*)(kvb + (size_t)sscl * 1024 + lane * 8);
      float d0 = 0.f;
#pragma unroll
      for (int i = 0; i < 4; ++i) {
        unsigned uu = kr[i];
        d0 = fmaf(qf[2 * i],     __uint_as_float(uu << 16),         d0);
        d0 = fmaf(qf[2 * i + 1], __uint_as_float(uu & 0xffff0000u), d0);
      }
      d0 += __shfl_xor(d0, 1);
      d0 += __shfl_xor(d0, 2);
      d0 += __shfl_xor(d0, 4);
      sc4[u] = (ss < cnt) ? d0 * 0.125f : -1e30f;
    }
    float cmax = fmaxf(fmaxf(sc4[0], sc4[1]), fmaxf(sc4[2], sc4[3]));
    float mn = fmaxf(m, cmax);
    float c = __expf(m - mn);
    float p[4];
#pragma unroll
    for (int u = 0; u < 4; ++u) p[u] = __expf(sc4[u] - mn);
    l = l * c + p[0] + p[1] + p[2] + p[3];
#pragma unroll
    for (int k = 0; k < 8; ++k) o[k] *= c;
#pragma unroll
    for (int u = 0; u < 4; ++u) {
      int ss = s + u;
      int sscl = (ss < cnt) ? ss : (cnt - 1);
      uint4v vr = *(const uint4v*)(kvb + (size_t)sscl * 1024 + 512 + lane * 8);
      float pu = p[u];
#pragma unroll
      for (int i = 0; i < 4; ++i) {
        unsigned uu = vr[i];
        o[2 * i]     = fmaf(pu, __uint_as_float(uu << 16),         o[2 * i]);
        o[2 * i + 1] = fmaf(pu, __uint_as_float(uu & 0xffff0000u), o[2 * i + 1]);
      }
    }
    m = mn;
  }
  float invl = 1.f / l;
  bf16 ob[8];
#pragma unroll
  for (int k = 0; k < 8; ++k) ob[k] = bf16(o[k] * invl);
  *(uint4v*)(ctx + qrow * 512 + lane * 8) = *(uint4v*)ob;
}

// ---------------------------------------------------------------------------
// layernorm of (queries + attn_out[bf16]) -> bf16 qn
// ---------------------------------------------------------------------------
__global__ __launch_bounds__(256) void k_ln(
    const float* __restrict__ emb, const float* __restrict__ lq,
    const bf16* __restrict__ attn,
    const float* __restrict__ g, const float* __restrict__ bb,
    bf16* __restrict__ qn)
{
  int r = blockIdx.x * 4 + (threadIdx.x >> 6);
  int lane = threadIdx.x & 63;
  int bn = r >> 2, j = r & 3;
  const float* src = (j == 0) ? emb + (size_t)bn * D_ : lq + (size_t)(j - 1) * D_;
  float h[8];
  float s = 0.f, s2 = 0.f;
#pragma unroll
  for (int i = 0; i < 8; ++i) {
    int d = i * 64 + lane;
    float v = src[d] + __bfloat162float(attn[(size_t)r * D_ + d]);
    h[i] = v; s += v; s2 += v * v;
  }
#pragma unroll
  for (int off = 32; off; off >>= 1) { s += __shfl_xor(s, off); s2 += __shfl_xor(s2, off); }
  float mean = s * (1.f / 512.f);
  float var = s2 * (1.f / 512.f) - mean * mean;
  float inv = rsqrtf(var + 1e-5f);
#pragma unroll
  for (int i = 0; i < 8; ++i) {
    int d = i * 64 + lane;
    qn[(size_t)r * D_ + d] = bf16((h[i] - mean) * inv * g[d] + bb[d]);
  }
}

// ---------------------------------------------------------------------------
// fused bottleneck epilogue + mu/logvar/z + KL partial
// ---------------------------------------------------------------------------
__global__ __launch_bounds__(128) void k_muz(
    const float* __restrict__ part, const float* __restrict__ bbias,
    const float* __restrict__ pooled,
    const float* __restrict__ mu_w, const float* __restrict__ mu_b,
    const float* __restrict__ lv_w, const float* __restrict__ lv_b,
    const float* __restrict__ eps, float* __restrict__ z, float* __restrict__ klpart)
{
  __shared__ float hs[512];
  __shared__ float ms[64], ls[64];
  int bn = blockIdx.x;
  int tid = threadIdx.x;
  const size_t S = 1024ull * 512;
  for (int i = tid; i < 512; i += 128) {
    size_t off = (size_t)bn * 512 + i;
    float v = part[off] + part[off + S] + part[off + 2 * S] + part[off + 3 * S] + bbias[i];
    v = v / (1.f + __expf(-v));
    hs[i] = v + pooled[off];
  }
  __syncthreads();
  int ld = tid & 63;
  const float* wrow = (tid < 64) ? (mu_w + (size_t)ld * 512) : (lv_w + (size_t)ld * 512);
  float acc = 0.f;
  for (int k = 0; k < 512; ++k) acc = fmaf(hs[k], wrow[k], acc);
  acc += (tid < 64) ? mu_b[ld] : lv_b[ld];
  if (tid < 64) ms[ld] = acc; else ls[ld] = acc;
  __syncthreads();
  if (tid < 64) {
    float mu = ms[ld], lv = ls[ld];
    z[(size_t)bn * 64 + ld] = mu + eps[(size_t)bn * 64 + ld] * expf(0.5f * lv);
    float klt = 1.f + lv - mu * mu - expf(lv);
#pragma unroll
    for (int off = 32; off; off >>= 1) klt += __shfl_xor(klt, off);
    if (ld == 0) klpart[bn] = klt;
  }
}

// ---------------------------------------------------------------------------
// im2col A for conv1 (azc bf16 [8192][256]), 8 k-elems/thread, 16B stores,
// + y1p pad-row zeroing fused. grid = 1024 blocks.
// ---------------------------------------------------------------------------
__global__ __launch_bounds__(256) void k_azc(
    const float* __restrict__ z, const int* __restrict__ idx,
    const int* __restrict__ segst, const int* __restrict__ dur,
    bf16* __restrict__ azc, bf16* __restrict__ y1p)
{
  int gid = blockIdx.x * 256 + threadIdx.x;     // [0, 262144)
  if (blockIdx.x < 32) {
    int d = gid & 511;
    int rest = gid >> 9;
    int which = rest & 1;
    int b = rest >> 1;
    int rr = which ? (T_ + 1) : 0;
    y1p[(size_t)(b * (T_ + 2) + rr) * 512 + d] = bf16(0.f);
  }
  int m = gid >> 5;                             // [0, 8192)
  int k0 = (gid & 31) * 8;
  int b = m >> 10, t = m & 1023;
  bf16 tmp[8];
#pragma unroll
  for (int e = 0; e < 8; ++e) {
    int k = k0 + e;
    float v = 0.f;
    if (k < 195) {
      int tap = k / 65, c = k - tap * 65;
      int tt = t + tap - 1;
      if (tt >= 0 && tt < T_) {
        int iv = idx[b * T_ + tt];
        if (c < 64) v = z[(size_t)(b * N_ + iv) * 64 + c];
        else {
          int s0 = segst[b * N_ + iv];
          float d2 = (float)dur[b * N_ + iv];
          v = ((float)(tt - s0) + 0.5f) / d2;
        }
      }
    }
    tmp[e] = bf16(v);
  }
  *(uint4v*)(azc + (size_t)m * 256 + k0) = *(uint4v*)tmp;
}

// ---------------------------------------------------------------------------
// final scalar outputs
// ---------------------------------------------------------------------------
__global__ __launch_bounds__(256) void k_final(
    const float* __restrict__ klpart, const float* __restrict__ lacc,
    const float* __restrict__ klw, float* __restrict__ out)
{
  __shared__ float sa[4];
  float a = 0.f;
  for (int i = threadIdx.x; i < 1024; i += 256) a += klpart[i];
#pragma unroll
  for (int off = 32; off; off >>= 1) a += __shfl_xor(a, off);
  int w = threadIdx.x >> 6, lane = threadIdx.x & 63;
  if (lane == 0) sa[w] = a;
  __syncthreads();
  if (threadIdx.x == 0) {
    float kl = sa[0] + sa[1] + sa[2] + sa[3];
    out[(size_t)B_ * T_ * D_]     = -0.5f * kl * klw[0];
    out[(size_t)B_ * T_ * D_ + 1] = (lacc[0] + lacc[1]) / (float)(B_ * T_ * D_);
  }
}

// ---------------------------------------------------------------------------
extern "C" void kernel_launch(void* const* d_in, const int* in_sizes, int n_in,
                              void* d_out, int out_size, void* d_ws, size_t ws_size,
                              hipStream_t stream)
{
  const float* emb  = (const float*)d_in[0];
  const float* algn = (const float*)d_in[1];
  const float* x    = (const float*)d_in[2];
  const float* klw  = (const float*)d_in[5];
  const float* eps  = (const float*)d_in[6];
  const float* lq   = (const float*)d_in[7];
  const float* inw  = (const float*)d_in[8];
  const float* inb  = (const float*)d_in[9];
  const float* outw = (const float*)d_in[10];
  const float* outb = (const float*)d_in[11];
  const float* lng  = (const float*)d_in[12];
  const float* lnb  = (const float*)d_in[13];
  const float* botw = (const float*)d_in[14];
  const float* botb = (const float*)d_in[15];
  const float* muw  = (const float*)d_in[16];
  const float* mub  = (const float*)d_in[17];
  const float* lvw  = (const float*)d_in[18];
  const float* lvb  = (const float*)d_in[19];
  const float* c1w  = (const float*)d_in[20];
  const float* c1b  = (const float*)d_in[21];
  const float* c2w  = (const float*)d_in[22];
  const float* c2b  = (const float*)d_in[23];
  float* out = (float*)d_out;

  float* ws = (float*)d_ws;
  size_t o = 0;
  auto allocF = [&](size_t n) { float* p = ws + o; o += n; return p; };
  auto allocB = [&](size_t n) { bf16* p = (bf16*)(ws + o); o += (n + 1) / 2; return p; };

  bf16* kvB    = allocB(8192ull * 1024);
  bf16* xb     = allocB(8192ull * 512);     // dead after kv GEMM; azc aliases it
  bf16* qryB   = allocB(4096ull * 512);     // embB + lqQb live here
  bf16* qbufB  = allocB(4096ull * 512);     // embQ (1024x512 used)
  bf16* ctxB   = allocB(4096ull * 512);
  bf16* qnB    = allocB(4096ull * 512);
  bf16* inwb   = allocB(1536ull * 512);
  bf16* outwb  = allocB(512ull * 512);
  bf16* botwb  = allocB(512ull * 2048);
  bf16* w1tb   = allocB(512ull * 256);
  bf16* w2tb   = allocB(512ull * 1536);
  bf16* y1p    = allocB(8ull * (T_ + 2) * 512);
  float* attnF  = allocF(4096ull * 512);    // attnB(bf16) then botP(fp32)
  float* pooled = allocF(1024ull * 512);
  float* zbuf   = allocF(1024ull * 64);
  float* klpart = allocF(1024);
  float* lacc   = allocF(2);
  int* idx   = (int*)(ws + o); o += 8192;
  int* segst = (int*)(ws + o); o += 1024;
  int* durI  = (int*)(ws + o); o += 1024;
  bf16* azc  = xb;
  bf16* embB = qryB;
  bf16* lqQb = qryB + 1024ull * 512;
  bf16* attnB = (bf16*)attnF;
  float* botP = attnF;

  // 1. mega-prep
  k_prep<<<dim3(13953), 256, 0, stream>>>(
      x, inw, outw, botw, c1w, c2w, emb, lq, algn, inb,
      xb, inwb, outwb, botwb, w1tb, w2tb, embB, lqQb, idx, durI, segst,
      lacc, pooled);

  // 2. kv + embQ projections (merged, XCD-swizzled, 512 thr)
  k_kvq<<<dim3(544), 512, 0, stream>>>(xb, embB, inwb, inb, kvB, qbufB);

  // 3. attention
  k_attn<<<dim3(B_ * N_), 256, 0, stream>>>(qbufB, lqQb, kvB, segst, durI, ctxB);

  // 4. out projection -> bf16 attnB
  k_outp<<<dim3(128), 512, 0, stream>>>(ctxB, outwb, outb, attnB);

  // 5. layernorm
  k_ln<<<dim3(1024), 256, 0, stream>>>(emb, lq, attnB, lng, lnb, qnB);

  // 6. bottleneck split-K=4 partials
  k_bot<<<dim3(32, 4), 512, 0, stream>>>(qnB, botwb, botP);

  // 7. fused bot-epilogue + VAE + KL
  k_muz<<<dim3(B_ * N_), 128, 0, stream>>>(
      botP, botb, pooled, muw, mub, lvw, lvb, eps, zbuf, klpart);

  // 8. conv1 im2col (vectorized) + y1p pad zeroing
  k_azc<<<dim3(1024), 256, 0, stream>>>(zbuf, idx, segst, durI, azc, y1p);

  // 9. conv1
  k_conv1<<<dim3(256), 512, 0, stream>>>(azc, w1tb, c1b, y1p);

  // 10. conv2 + fused loss
  k_conv2<<<dim3(256), 512, 0, stream>>>(y1p, w2tb, c2b, out, x, lacc);

  // 11. final scalars
  k_final<<<dim3(1), 256, 0, stream>>>(klpart, lacc, klw, out);
}